// Round 2
// baseline (681.548 us; speedup 1.0000x reference)
//
#include <hip/hip_runtime.h>

#define NBINS   100
#define NBINS_P 101   // +1 spill slot so the k+1 tap is branch-free
#define NCOPY   64    // one LDS sub-histogram per lane-in-wave

// ---------------------------------------------------------------------------
// Kernel 1: zero the global bin accumulator in d_ws (poisoned 0xAA once,
// never re-poisoned -> must zero every call).
// ---------------------------------------------------------------------------
__global__ void histo_zero(float* __restrict__ g) {
    int i = threadIdx.x;
    if (i < NBINS) g[i] = 0.0f;
}

// ---------------------------------------------------------------------------
// Kernel 2: streaming pass. x in [0,1): k = floor(100x), t = frac(100x);
// bin k   += 0.01*(1-t)
// bin k+1 += 0.01*t      (k+1 == 100 lands in the spill slot, discarded)
// Per-lane LDS sub-histograms (copy = tid&63): ds_add_f32, never two lanes of
// one instruction on the same address. Stride 101 -> bank = (5*lane + k) % 32,
// perfect 2-way (free) even when all lanes share a bin.
// ---------------------------------------------------------------------------
__global__ __launch_bounds__(256) void histo_accum(const float* __restrict__ x,
                                                   float* __restrict__ gbins,
                                                   int n4, int n) {
    __shared__ float h[NCOPY * NBINS_P];
    const int tid  = threadIdx.x;
    const int lane = tid & (NCOPY - 1);
    const int base = lane * NBINS_P;

    for (int i = tid; i < NCOPY * NBINS_P; i += blockDim.x) h[i] = 0.0f;
    __syncthreads();

    const float4* __restrict__ x4 = (const float4*)x;
    const int stride = gridDim.x * blockDim.x;

    int i = blockIdx.x * blockDim.x + tid;

#define PROCESS4(v)                                                \
    {                                                              \
        float vv[4] = {(v).x, (v).y, (v).z, (v).w};                \
        _Pragma("unroll")                                          \
        for (int j = 0; j < 4; ++j) {                              \
            float xf = vv[j] * 100.0f;                             \
            float fk = floorf(xf);                                 \
            int   k  = min((int)fk, NBINS - 1);                    \
            float w1 = (xf - fk) * 0.01f;                          \
            float w0 = 0.01f - w1;                                 \
            atomicAdd(&h[base + k], w0);                           \
            atomicAdd(&h[base + k + 1], w1);                       \
        }                                                          \
    }

    // 2-deep load pipeline: two independent float4 loads in flight
    for (; i + stride < n4; i += 2 * stride) {
        float4 a = x4[i];
        float4 b = x4[i + stride];
        PROCESS4(a);
        PROCESS4(b);
    }
    if (i < n4) {
        float4 a = x4[i];
        PROCESS4(a);
    }

    // scalar tail (n % 4 != 0) — block 0 only
    if (blockIdx.x == 0) {
        for (int t = n4 * 4 + tid; t < n; t += blockDim.x) {
            float xf = x[t] * 100.0f;
            float fk = floorf(xf);
            int   k  = min((int)fk, NBINS - 1);
            float w1 = (xf - fk) * 0.01f;
            float w0 = 0.01f - w1;
            atomicAdd(&h[base + k], w0);
            atomicAdd(&h[base + k + 1], w1);
        }
    }
#undef PROCESS4

    __syncthreads();

    // reduce NCOPY copies -> one partial per bin -> one global atomic per bin
    for (int b = tid; b < NBINS; b += blockDim.x) {
        float s = 0.0f;
#pragma unroll
        for (int c = 0; c < NCOPY; ++c) s += h[c * NBINS_P + b];
        unsafeAtomicAdd(&gbins[b], s);   // global fp32 fadd (intended use)
    }
}

// ---------------------------------------------------------------------------
// Kernel 3: normalize — out[i] = g[i] / (sum(g) + 1e-6). One block, 128 thr.
// ---------------------------------------------------------------------------
__global__ void histo_final(const float* __restrict__ g, float* __restrict__ out) {
    __shared__ float wsum[2];
    const int t = threadIdx.x;           // 128 threads = 2 waves
    float v = (t < NBINS) ? g[t] : 0.0f;

    float s = v;
#pragma unroll
    for (int o = 32; o > 0; o >>= 1) s += __shfl_down(s, o, 64);
    if ((t & 63) == 0) wsum[t >> 6] = s;
    __syncthreads();

    float total = wsum[0] + wsum[1];
    if (t < NBINS) out[t] = v / (total + 1e-6f);
}

extern "C" void kernel_launch(void* const* d_in, const int* in_sizes, int n_in,
                              void* d_out, int out_size, void* d_ws, size_t ws_size,
                              hipStream_t stream) {
    const float* x   = (const float*)d_in[0];  // [64 * 1048576] fp32 in [0,1)
    float*       out = (float*)d_out;          // [100] fp32
    float*       g   = (float*)d_ws;           // 100-float accumulator

    const int n  = in_sizes[0];
    const int n4 = n / 4;

    histo_zero<<<1, 128, 0, stream>>>(g);

    const int block  = 256;
    int blocks = 1536;                          // 6 blocks/CU (25.9 KB LDS each)
    int need   = (n4 + block - 1) / block;
    if (blocks > need) blocks = need;
    histo_accum<<<blocks, block, 0, stream>>>(x, g, n4, n);

    histo_final<<<1, 128, 0, stream>>>(g, out);
}

// Round 3
// 95.996 us; speedup vs baseline: 7.0997x; 7.0997x over previous
//
#include <hip/hip_runtime.h>

#define NBINS  100
#define NROWS  101              // +1 spill row: k+1==100 tap is discarded
#define BLK    64               // one wave per block; copy == lane (exclusive)

// ---------------------------------------------------------------------------
// Kernel 1: zero the global bin accumulator in d_ws (poisoned 0xAA once).
// ---------------------------------------------------------------------------
__global__ void histo_zero(float* __restrict__ g) {
    int i = threadIdx.x;
    if (i < NBINS) g[i] = 0.0f;
}

// ---------------------------------------------------------------------------
// Kernel 2: streaming pass, NO atomics in the hot loop.
// Each thread owns column `lane` of h[101][64]: RMW via plain ds_read/ds_write
// (fp32 LDS atomics are a ~3 cyc/lane serialized unit — measured R1/R2).
// Bin-major layout: addr = k*64+lane -> bank = lane%32, conflict-free for any
// k; the (k, k+1) pair maps to ds_read2st64/ds_write2st64.
// ---------------------------------------------------------------------------
__global__ __launch_bounds__(BLK) void histo_accum(const float* __restrict__ x,
                                                   float* __restrict__ gbins,
                                                   int n4, int n) {
    __shared__ float h[NROWS * BLK];
    const int lane = threadIdx.x;

    for (int i = lane; i < NROWS * BLK; i += BLK) h[i] = 0.0f;
    __syncthreads();

#define PROC(v)                                              \
    {                                                        \
        float xf = (v) * 100.0f;                             \
        float fk = floorf(xf);                               \
        int   k  = min((int)fk, NBINS - 1);                  \
        float w1 = (xf - fk) * 0.01f;                        \
        float w0 = 0.01f - w1;                               \
        int   a  = k * BLK + lane;                           \
        float c0 = h[a];                                     \
        float c1 = h[a + BLK];                               \
        h[a]       = c0 + w0;                                \
        h[a + BLK] = c1 + w1;                                \
    }

#define PROC4(v) { PROC((v).x); PROC((v).y); PROC((v).z); PROC((v).w); }

    const float4* __restrict__ x4 = (const float4*)x;
    const int stride = gridDim.x * BLK;
    int i = blockIdx.x * BLK + lane;

    // 4 independent float4 loads in flight per wave
    for (; i + 3 * stride < n4; i += 4 * stride) {
        float4 a = x4[i];
        float4 b = x4[i + stride];
        float4 c = x4[i + 2 * stride];
        float4 d = x4[i + 3 * stride];
        PROC4(a); PROC4(b); PROC4(c); PROC4(d);
    }
    for (; i < n4; i += stride) {
        float4 a = x4[i];
        PROC4(a);
    }

    // scalar tail (n % 4) — block 0 only
    if (blockIdx.x == 0) {
        for (int t = n4 * 4 + lane; t < n; t += BLK) {
            float v = x[t];
            PROC(v);
        }
    }
#undef PROC4
#undef PROC

    __syncthreads();

    // Reduce 64 copies per bin. Diagonal sweep keeps banks distinct
    // (addr = b*64 + (c+lane)&63 -> bank = (c+lane)%32, 2-way = free).
    for (int b = lane; b < NBINS; b += BLK) {
        float s = 0.0f;
#pragma unroll
        for (int c = 0; c < BLK; ++c) {
            int cc = (c + lane) & (BLK - 1);
            s += h[b * BLK + cc];
        }
        unsafeAtomicAdd(&gbins[b], s);   // 100 global atomics per block
    }
}

// ---------------------------------------------------------------------------
// Kernel 3: normalize — out[i] = g[i] / (sum(g) + 1e-6). One block, 128 thr.
// ---------------------------------------------------------------------------
__global__ void histo_final(const float* __restrict__ g, float* __restrict__ out) {
    __shared__ float wsum[2];
    const int t = threadIdx.x;           // 128 threads = 2 waves
    float v = (t < NBINS) ? g[t] : 0.0f;

    float s = v;
#pragma unroll
    for (int o = 32; o > 0; o >>= 1) s += __shfl_down(s, o, 64);
    if ((t & 63) == 0) wsum[t >> 6] = s;
    __syncthreads();

    float total = wsum[0] + wsum[1];
    if (t < NBINS) out[t] = v / (total + 1e-6f);
}

extern "C" void kernel_launch(void* const* d_in, const int* in_sizes, int n_in,
                              void* d_out, int out_size, void* d_ws, size_t ws_size,
                              hipStream_t stream) {
    const float* x   = (const float*)d_in[0];  // [64 * 1048576] fp32 in [0,1)
    float*       out = (float*)d_out;          // [100] fp32
    float*       g   = (float*)d_ws;           // 100-float accumulator

    const int n  = in_sizes[0];
    const int n4 = n / 4;

    histo_zero<<<1, 128, 0, stream>>>(g);

    int blocks = 1536;                          // 6 blocks/CU (25.9 KB LDS each)
    int need   = (n4 + BLK - 1) / BLK;
    if (blocks > need) blocks = need;
    histo_accum<<<blocks, BLK, 0, stream>>>(x, g, n4, n);

    histo_final<<<1, 128, 0, stream>>>(g, out);
}